// Round 12
// baseline (584.480 us; speedup 1.0000x reference)
//
#include <hip/hip_runtime.h>
#include <cstdint>
#include <cstddef>

// ---------------------------------------------------------------------------
// BsPINN forward, single-fp16 MFMA, producer/consumer K-loop (round 12).
// R11 green: 496us, absmax 2.44e-4, layer1 ~750 TF, MfmaUtil 32%.
// R12: the two-barrier K-loop's vmcnt(0)-drain-at-barrier is the plateau
// (guide: restructure, don't tweak). Block = 5 waves: waves 0-3 consume
// (R10's proven 128x128 fragment path, 64x64 per wave), wave 4 produces
// (global->regs->LDS into double buffer). One barrier/iter; consumer waves
// have NO outstanding global loads at barriers -> their drain is free.
//   h0 = tanh(norm(X) @ W0 + b0)        K=2   fp32 vector
//   h1 = tanh(h0 @ W1 + b1)             K=1024 MFMA f16
//   h2 = tanh(h1 @ (W2*m2) + b2)        2 x 512 block-diag (K=512)
//   out = tanh(h2 @ (W3*m3) + b3) @ W_last + b_last   (fused, K=256)
// ---------------------------------------------------------------------------

typedef _Float16  f16x8   __attribute__((ext_vector_type(8)));
typedef float     floatx4 __attribute__((ext_vector_type(4)));
typedef float     floatx8 __attribute__((ext_vector_type(8)));

__device__ __forceinline__ float tanh_fast(float x) {
    float e = __expf(2.0f * x);
    return 1.0f - 2.0f / (e + 1.0f);
}

// ---------------------------------------------------------------------------
// Weight transpose + f16 convert, all three weights in one launch (z picks).
// fp32 W[K=1024][N=1024] -> f16 Wt[N][K].
// ---------------------------------------------------------------------------
__global__ __launch_bounds__(256)
void transposeH3(const float* __restrict__ W1, const float* __restrict__ W2,
                 const float* __restrict__ W3, _Float16* __restrict__ Wt1,
                 _Float16* __restrict__ Wt2, _Float16* __restrict__ Wt3) {
    const float* W = blockIdx.z == 0 ? W1 : (blockIdx.z == 1 ? W2 : W3);
    _Float16* Wt   = blockIdx.z == 0 ? Wt1 : (blockIdx.z == 1 ? Wt2 : Wt3);
    __shared__ float tile[32][33];
    const int tx = threadIdx.x & 31;
    const int ty = threadIdx.x >> 5;     // 0..7
    #pragma unroll
    for (int j = 0; j < 4; ++j) {
        int r = ty + j * 8;
        tile[r][tx] = W[(size_t)(blockIdx.y * 32 + r) * 1024 + blockIdx.x * 32 + tx];
    }
    __syncthreads();
    #pragma unroll
    for (int j = 0; j < 4; ++j) {
        int r = ty + j * 8;
        Wt[(size_t)(blockIdx.x * 32 + r) * 1024 + blockIdx.y * 32 + tx] =
            (_Float16)tile[tx][r];
    }
}

// ---------------------------------------------------------------------------
// out[row] := b_last — re-initialized every call before layer3 atomics.
// ---------------------------------------------------------------------------
__global__ __launch_bounds__(256)
void init_out(float* __restrict__ out, const float* __restrict__ bl) {
    out[blockIdx.x * 256 + threadIdx.x] = bl[0];
}

// ---------------------------------------------------------------------------
// Layer 0 (fp32 in): h0 = tanh(xa*W0[0][:] + xb*W0[1][:] + b0) -> f16.
// ---------------------------------------------------------------------------
__global__ __launch_bounds__(256)
void layer0_kernel(const float* __restrict__ X, const float* __restrict__ W0,
                   const float* __restrict__ b0, _Float16* __restrict__ H) {
    const int idx = blockIdx.x * 256 + threadIdx.x;
    const int row = idx >> 7;
    const int j0  = (idx & 127) << 3;
    const float x0 = X[row * 2 + 0];
    const float x1 = X[row * 2 + 1];
    const float xa = x0 * 0.31830988618379067f - 1.0f;   // x0/pi - 1
    const float xb = 2.0f * x1 - 1.0f;
    floatx8 wa = *(const floatx8*)(W0 + j0);
    floatx8 wb = *(const floatx8*)(W0 + 1024 + j0);
    floatx8 bb = *(const floatx8*)(b0 + j0);
    f16x8 o;
    #pragma unroll
    for (int j = 0; j < 8; ++j) {
        float v = fmaf(xa, wa[j], fmaf(xb, wb[j], bb[j]));
        o[j] = (_Float16)tanh_fast(v);
    }
    *(f16x8*)(H + (size_t)row * 1024 + j0) = o;
}

// ---------------------------------------------------------------------------
// GEMM + bias + tanh, f16, producer/consumer. 128x128 tile, BK=32.
// 320 threads: waves 0-3 = consumers (2x2 of 64x64, 4x4 16x16x32 frags),
// wave 4 = producer (stages A 128x32 + B 128x32 = 16 KB into lds[t&1^1]).
// Double-buffered: producer writes buf[(t+1)&1] while consumers read
// buf[t&1]; single end-of-iter barrier. Consumers touch no global memory
// inside the loop -> no vmcnt stall at barriers.
// KB = diag block: cols [n0,n0+128) need k in [(n0/KB)*KB, +KB).
// FUSE: layer3+final — per-row partial of tanh(pre).Wl, 16-lane shfl
// reduce, one fp32 atomicAdd into out[row] (pre-initialized to b_last).
// ---------------------------------------------------------------------------
template <bool FUSE>
__global__ __launch_bounds__(320)
void gemm_tanh_f16(const _Float16* __restrict__ A, const _Float16* __restrict__ Bt,
                   const float* __restrict__ bias, _Float16* __restrict__ C,
                   const float* __restrict__ Wl, float* __restrict__ out, int KB) {
    __shared__ _Float16 lds[2][8192];    // [buf][A:0..4095 | B:4096..8191] 32 KB

    const int tid  = threadIdx.x;
    const int lane = tid & 63;
    const int wave = tid >> 6;           // 0..4
    const int m0 = blockIdx.x * 128;     // m fast (proven cache order)
    const int n0 = blockIdx.y * 128;
    const int kbeg   = (n0 / KB) * KB;
    const int kiters = KB >> 5;

    if (wave == 4) {
        // ---------------- producer ----------------
        // slot s = lane + 64*i (i<8): row = s>>2 (0..127), seg = (s&3)*8.
        // ga[i] = ga[0] + i*16*1024 (row strides 16 per i); ls strides 512.
        const int row0 = lane >> 2;
        const int sg   = (lane & 3) << 3;
        const size_t gaBase = (size_t)(m0 + row0) * 1024 + kbeg + sg;
        const size_t gbBase = (size_t)(n0 + row0) * 1024 + kbeg + sg;
        const int lsBase = lane * 8;     // elem offset; strides 512 per i
        f16x8 ra[8], rb[8];
        #pragma unroll
        for (int i = 0; i < 8; ++i) {
            ra[i] = *(const f16x8*)(A + gaBase + (size_t)i * 16384);
            rb[i] = *(const f16x8*)(Bt + gbBase + (size_t)i * 16384);
        }
        #pragma unroll
        for (int i = 0; i < 8; ++i) {
            *(f16x8*)(&lds[0][lsBase + i * 512]) = ra[i];
            *(f16x8*)(&lds[0][4096 + lsBase + i * 512]) = rb[i];
        }
        __syncthreads();                 // buf0 ready
        for (int t = 0; t < kiters; ++t) {
            if (t + 1 < kiters) {
                const size_t d = (size_t)(t + 1) << 5;
                #pragma unroll
                for (int i = 0; i < 8; ++i) {
                    ra[i] = *(const f16x8*)(A + gaBase + (size_t)i * 16384 + d);
                    rb[i] = *(const f16x8*)(Bt + gbBase + (size_t)i * 16384 + d);
                }
                _Float16* dst = lds[(t + 1) & 1];
                #pragma unroll
                for (int i = 0; i < 8; ++i) {
                    *(f16x8*)(dst + lsBase + i * 512) = ra[i];
                    *(f16x8*)(dst + 4096 + lsBase + i * 512) = rb[i];
                }
            }
            __syncthreads();             // tile t+1 published; t consumed
        }
        return;                          // consumers run epilogue barrier-free
    }

    // ---------------- consumers (waves 0-3) ----------------
    const int wm = (wave & 1) << 6;
    const int wn = (wave >> 1) << 6;
    const int r = lane & 15;
    const int q = lane >> 4;

    floatx4 acc[4][4];
    #pragma unroll
    for (int i = 0; i < 4; ++i)
        #pragma unroll
        for (int j = 0; j < 4; ++j)
            acc[i][j] = floatx4{0.f, 0.f, 0.f, 0.f};

    __syncthreads();                     // matches producer prologue barrier
    for (int t = 0; t < kiters; ++t) {
        const _Float16* As = lds[t & 1];
        const _Float16* Bs = As + 4096;
        f16x8 af[4], bf[4];
        #pragma unroll
        for (int i = 0; i < 4; ++i) {
            af[i] = *(const f16x8*)(As + (wm + i * 16 + r) * 32 + q * 8);
            bf[i] = *(const f16x8*)(Bs + (wn + i * 16 + r) * 32 + q * 8);
        }
        #pragma unroll
        for (int i = 0; i < 4; ++i)
            #pragma unroll
            for (int j = 0; j < 4; ++j)
                acc[i][j] = __builtin_amdgcn_mfma_f32_16x16x32_f16(af[i], bf[j], acc[i][j], 0, 0, 0);
        __syncthreads();
    }

    // Epilogue. C/D layout: col=lane&15, row=(lane>>4)*4+reg.
    float bv[4], wlv[4];
    #pragma unroll
    for (int j = 0; j < 4; ++j) {
        const int col = n0 + wn + j * 16 + r;
        bv[j] = bias[col];
        if (FUSE) wlv[j] = Wl[col];
    }
    #pragma unroll
    for (int i = 0; i < 4; ++i) {
        const int row0 = m0 + wm + i * 16 + q * 4;
        #pragma unroll
        for (int rr = 0; rr < 4; ++rr) {
            if (!FUSE) {
                #pragma unroll
                for (int j = 0; j < 4; ++j) {
                    float o = tanh_fast(acc[i][j][rr] + bv[j]);
                    const int col = n0 + wn + j * 16 + r;
                    C[(size_t)(row0 + rr) * 1024 + col] = (_Float16)o;
                }
            } else {
                float p = 0.f;
                #pragma unroll
                for (int j = 0; j < 4; ++j)
                    p = fmaf(tanh_fast(acc[i][j][rr] + bv[j]), wlv[j], p);
                p += __shfl_down(p, 8);  // reduce the 16 r-lanes
                p += __shfl_down(p, 4);
                p += __shfl_down(p, 2);
                p += __shfl_down(p, 1);
                if (r == 0) atomicAdd(out + row0 + rr, p);
            }
        }
    }
}

// ---------------------------------------------------------------------------
extern "C" void kernel_launch(void* const* d_in, const int* in_sizes, int n_in,
                              void* d_out, int out_size, void* d_ws, size_t ws_size,
                              hipStream_t stream) {
    const float* X  = (const float*)d_in[0];
    const float* W0 = (const float*)d_in[1];
    const float* b0 = (const float*)d_in[2];
    const float* W1 = (const float*)d_in[3];
    const float* b1 = (const float*)d_in[4];
    const float* W2 = (const float*)d_in[5];
    const float* b2 = (const float*)d_in[6];
    const float* W3 = (const float*)d_in[7];
    const float* b3 = (const float*)d_in[8];
    const float* Wl = (const float*)d_in[9];
    const float* bl = (const float*)d_in[10];
    float* out = (float*)d_out;

    const int Nrows = in_sizes[0] / 2;                 // 65536
    const size_t WT = 1024 * 1024;                     // elems per f16 weight plane
    const size_t wt_bytes = 3 * WT * 2;                // 6 MiB
    const size_t slack = 512;

    // chunk rows R (pow2): 2 f16 activation planes must fit ws.
    int R = 0;
    const int Rcap = Nrows < 32768 ? Nrows : 32768;
    for (int r = Rcap; r >= 256; r >>= 1)
        if ((size_t)2 * r * 2048 + wt_bytes + slack <= ws_size) { R = r; break; }
    if (!R) return;

    _Float16* wsp = (_Float16*)d_ws;
    _Float16* Wt1 = wsp;
    _Float16* Wt2 = Wt1 + WT;
    _Float16* Wt3 = Wt2 + WT;
    const size_t plane = (size_t)R * 1024;
    _Float16* P0 = Wt3 + WT;
    _Float16* P1 = P0 + plane;

    const dim3 tb(256);
    transposeH3<<<dim3(32, 32, 3), tb, 0, stream>>>(W1, W2, W3, Wt1, Wt2, Wt3);
    init_out<<<Nrows / 256, tb, 0, stream>>>(out, bl);

    const int nchunks = Nrows / R;
    for (int c = 0; c < nchunks; ++c) {
        const float* Xc = X + (size_t)c * R * 2;
        float* outc = out + (size_t)c * R;

        layer0_kernel<<<R / 2, tb, 0, stream>>>(Xc, W0, b0, P0);

        const dim3 tg(320);
        const dim3 gg(R / 128, 8);                    // m fast
        gemm_tanh_f16<false><<<gg, tg, 0, stream>>>(P0, Wt1, b1, P1, nullptr, nullptr, 1024);
        gemm_tanh_f16<false><<<gg, tg, 0, stream>>>(P1, Wt2, b2, P0, nullptr, nullptr, 512);
        gemm_tanh_f16<true ><<<gg, tg, 0, stream>>>(P0, Wt3, b3, nullptr, Wl, outc, 256);
    }
}